// Round 1
// baseline (944.025 us; speedup 1.0000x reference)
//
#include <hip/hip_runtime.h>

// out[i] = sum_{e: rows[e]==i} Param_W[params[e]] * x[cols[e]]  + Param_b[b_params[i]]
// N = 262144, E = 16777216 (E % 4 == 0), NPARAMS = 1280, NB = 16.

__global__ __launch_bounds__(256) void bias_init_kernel(const float* __restrict__ Pb,
                                                        const int* __restrict__ bp,
                                                        float* __restrict__ out, int n) {
    int i = blockIdx.x * 256 + threadIdx.x;
    if (i < n) out[i] = Pb[bp[i]];
}

__global__ __launch_bounds__(256) void edge_scatter4_kernel(const float* __restrict__ x,
                                                            const float* __restrict__ PW,
                                                            const int4* __restrict__ rows4,
                                                            const int4* __restrict__ cols4,
                                                            const int4* __restrict__ params4,
                                                            float* __restrict__ out, int e4) {
    int t = blockIdx.x * 256 + threadIdx.x;
    if (t >= e4) return;
    int4 r = rows4[t];
    int4 c = cols4[t];
    int4 p = params4[t];
    // gathers: x is 1 MB (L2-resident), PW is 5 KB (L1-resident)
    float v0 = PW[p.x] * x[c.x];
    float v1 = PW[p.y] * x[c.y];
    float v2 = PW[p.z] * x[c.z];
    float v3 = PW[p.w] * x[c.w];
    atomicAdd(out + r.x, v0);
    atomicAdd(out + r.y, v1);
    atomicAdd(out + r.z, v2);
    atomicAdd(out + r.w, v3);
}

__global__ __launch_bounds__(256) void edge_scatter_tail_kernel(const float* __restrict__ x,
                                                                const float* __restrict__ PW,
                                                                const int* __restrict__ rows,
                                                                const int* __restrict__ cols,
                                                                const int* __restrict__ params,
                                                                float* __restrict__ out,
                                                                int start, int E) {
    int e = start + blockIdx.x * 256 + threadIdx.x;
    if (e < E) atomicAdd(out + rows[e], PW[params[e]] * x[cols[e]]);
}

extern "C" void kernel_launch(void* const* d_in, const int* in_sizes, int n_in,
                              void* d_out, int out_size, void* d_ws, size_t ws_size,
                              hipStream_t stream) {
    const float* x        = (const float*)d_in[0];
    const float* Param_W  = (const float*)d_in[1];
    const float* Param_b  = (const float*)d_in[2];
    const int*   w_rows   = (const int*)d_in[3];
    const int*   w_cols   = (const int*)d_in[4];
    const int*   w_params = (const int*)d_in[5];
    const int*   b_params = (const int*)d_in[6];
    float* out = (float*)d_out;

    const int N_ = in_sizes[0];   // 262144
    const int E_ = in_sizes[3];   // 16777216

    // 1) out[i] = Param_b[b_params[i]]  (d_out is poisoned each call)
    bias_init_kernel<<<(N_ + 255) / 256, 256, 0, stream>>>(Param_b, b_params, out, N_);

    // 2) edge scatter, 4 edges per thread via int4 loads
    const int e4 = E_ / 4;
    if (e4 > 0) {
        edge_scatter4_kernel<<<(e4 + 255) / 256, 256, 0, stream>>>(
            x, Param_W, (const int4*)w_rows, (const int4*)w_cols, (const int4*)w_params,
            out, e4);
    }
    const int tail_start = e4 * 4;
    if (tail_start < E_) {
        const int tail = E_ - tail_start;
        edge_scatter_tail_kernel<<<(tail + 255) / 256, 256, 0, stream>>>(
            x, Param_W, w_rows, w_cols, w_params, out, tail_start, E_);
    }
}

// Round 2
// 438.976 us; speedup vs baseline: 2.1505x; 2.1505x over previous
//
#include <hip/hip_runtime.h>

// out[i] = sum_{e: rows[e]==i} Param_W[params[e]] * x[cols[e]] + Param_b[b_params[i]]
// N = 262144, E = 16777216, NPARAMS = 1280, NB = 16.
//
// Strategy: device-scope atomics measured at only ~20.6 G/s with 32 B write-through
// each (WRITE_SIZE 524 MB for a 1 MB output). Replace scatter-atomics with
// slice-partitioned LDS accumulation:
//   - 8 slices x 32768 outputs (128 KiB fp32 in LDS, 1 block/CU, 16 waves)
//   - 32 edge-chunks per slice -> 256 blocks, each scans 524288 edges,
//     filters rows by slice, accumulates via LDS atomics (ds_add_f32)
//   - partials (32 MiB) in d_ws, reduced + bias by a second coalesced kernel.

#define SLICE_BITS   15
#define SLICE_SIZE   (1 << SLICE_BITS)   // 32768
#define SLICES       8                   // N / SLICE_SIZE
#define CHUNKS       32                  // edge chunks per slice
#define SCAN_THREADS 1024

__global__ __launch_bounds__(SCAN_THREADS) void slice_scan_kernel(
    const float* __restrict__ x, const float* __restrict__ PW,
    const int4* __restrict__ rows4, const int4* __restrict__ cols4,
    const int4* __restrict__ params4, float* __restrict__ partials,
    int e4_per_chunk)
{
    __shared__ float acc[SLICE_SIZE];   // 128 KiB
    const int bid = blockIdx.x;
    const int s = bid / CHUNKS;         // slice
    const int c = bid % CHUNKS;         // chunk; same c -> same bid%8 -> same XCD
                                        // (round-robin dispatch heuristic: 8 slice-
                                        // readers of a chunk share one XCD's L2)
    for (int j = threadIdx.x; j < SLICE_SIZE; j += SCAN_THREADS) acc[j] = 0.0f;
    __syncthreads();

    const int base4 = c * e4_per_chunk;
    for (int it = threadIdx.x; it < e4_per_chunk; it += SCAN_THREADS) {
        const int4 r = rows4[base4 + it];
        const bool hx = (r.x >> SLICE_BITS) == s;
        const bool hy = (r.y >> SLICE_BITS) == s;
        const bool hz = (r.z >> SLICE_BITS) == s;
        const bool hw = (r.w >> SLICE_BITS) == s;
        if (hx | hy | hz | hw) {        // ~41% of threads per group of 4 edges
            const int4 cc = cols4[base4 + it];
            const int4 p  = params4[base4 + it];
            if (hx) atomicAdd(&acc[r.x & (SLICE_SIZE - 1)], PW[p.x] * x[cc.x]);
            if (hy) atomicAdd(&acc[r.y & (SLICE_SIZE - 1)], PW[p.y] * x[cc.y]);
            if (hz) atomicAdd(&acc[r.z & (SLICE_SIZE - 1)], PW[p.z] * x[cc.z]);
            if (hw) atomicAdd(&acc[r.w & (SLICE_SIZE - 1)], PW[p.w] * x[cc.w]);
        }
    }
    __syncthreads();

    float* dst = partials + (size_t)bid * SLICE_SIZE;
    for (int j = threadIdx.x; j < SLICE_SIZE; j += SCAN_THREADS) dst[j] = acc[j];
}

__global__ __launch_bounds__(256) void reduce_bias_kernel(
    const float* __restrict__ partials, const float* __restrict__ Pb,
    const int* __restrict__ bp, float* __restrict__ out, int n)
{
    const int i = blockIdx.x * 256 + threadIdx.x;
    if (i >= n) return;
    const int s = i >> SLICE_BITS;
    const int j = i & (SLICE_SIZE - 1);
    const float* p = partials + ((size_t)s * CHUNKS) * SLICE_SIZE + j;
    float sum = 0.0f;
#pragma unroll
    for (int g = 0; g < CHUNKS; ++g) sum += p[(size_t)g * SLICE_SIZE];
    out[i] = sum + Pb[bp[i]];
}

// ---------------- fallback path (round-1 atomic scatter) ----------------

__global__ __launch_bounds__(256) void bias_init_kernel(const float* __restrict__ Pb,
                                                        const int* __restrict__ bp,
                                                        float* __restrict__ out, int n) {
    int i = blockIdx.x * 256 + threadIdx.x;
    if (i < n) out[i] = Pb[bp[i]];
}

__global__ __launch_bounds__(256) void edge_scatter_kernel(const float* __restrict__ x,
                                                           const float* __restrict__ PW,
                                                           const int* __restrict__ rows,
                                                           const int* __restrict__ cols,
                                                           const int* __restrict__ params,
                                                           float* __restrict__ out, int E) {
    int e = blockIdx.x * 256 + threadIdx.x;
    if (e < E) atomicAdd(out + rows[e], PW[params[e]] * x[cols[e]]);
}

extern "C" void kernel_launch(void* const* d_in, const int* in_sizes, int n_in,
                              void* d_out, int out_size, void* d_ws, size_t ws_size,
                              hipStream_t stream) {
    const float* x        = (const float*)d_in[0];
    const float* Param_W  = (const float*)d_in[1];
    const float* Param_b  = (const float*)d_in[2];
    const int*   w_rows   = (const int*)d_in[3];
    const int*   w_cols   = (const int*)d_in[4];
    const int*   w_params = (const int*)d_in[5];
    const int*   b_params = (const int*)d_in[6];
    float* out = (float*)d_out;

    const int N_ = in_sizes[0];   // 262144
    const int E_ = in_sizes[3];   // 16777216

    const size_t ws_needed = (size_t)SLICES * CHUNKS * SLICE_SIZE * sizeof(float); // 32 MiB
    const bool shape_ok = (N_ == SLICES * SLICE_SIZE) && (E_ % (4 * CHUNKS) == 0);

    if (shape_ok && ws_size >= ws_needed) {
        float* partials = (float*)d_ws;
        const int e4_per_chunk = E_ / 4 / CHUNKS;   // 131072
        slice_scan_kernel<<<SLICES * CHUNKS, SCAN_THREADS, 0, stream>>>(
            x, Param_W, (const int4*)w_rows, (const int4*)w_cols, (const int4*)w_params,
            partials, e4_per_chunk);
        reduce_bias_kernel<<<(N_ + 255) / 256, 256, 0, stream>>>(
            partials, Param_b, b_params, out, N_);
    } else {
        bias_init_kernel<<<(N_ + 255) / 256, 256, 0, stream>>>(Param_b, b_params, out, N_);
        edge_scatter_kernel<<<(E_ + 255) / 256, 256, 0, stream>>>(
            x, Param_W, w_rows, w_cols, w_params, out, E_);
    }
}

// Round 3
// 368.501 us; speedup vs baseline: 2.5618x; 1.1912x over previous
//
#include <hip/hip_runtime.h>

// out[i] = sum_{e: rows[e]==i} Param_W[params[e]] * x[cols[e]] + Param_b[b_params[i]]
// N = 262144, E = 16777216, NPARAMS = 1280, NB = 16.
//
// R2 scan was latency-bound (all pipes idle: HBM 5.6%, VALU 13%, occ 44%).
// R3: batch-4 unconditional index loads (12 independent 16B loads in flight
// per thread), PW staged in LDS, keeping the 8-slice LDS-accumulate structure.

#define SLICE_BITS   15
#define SLICE_SIZE   (1 << SLICE_BITS)   // 32768
#define SLICES       8                   // N / SLICE_SIZE
#define CHUNKS       32                  // edge chunks per slice
#define SCAN_THREADS 1024
#define BATCH        4
#define NPARAMS_MAX  2048                // >= actual NPARAMS (1280)

__global__ __launch_bounds__(SCAN_THREADS, 1) void slice_scan_kernel(
    const float* __restrict__ x, const float* __restrict__ PW, int nparams,
    const int4* __restrict__ rows4, const int4* __restrict__ cols4,
    const int4* __restrict__ params4, float* __restrict__ partials,
    int e4_per_chunk)
{
    __shared__ float acc[SLICE_SIZE];    // 128 KiB
    __shared__ float pw_lds[NPARAMS_MAX]; // 8 KiB
    const int bid = blockIdx.x;
    const int s = bid / CHUNKS;          // slice
    const int c = bid % CHUNKS;          // chunk; bid%8 == c%8 -> the 8 slice-readers
                                         // of a chunk co-locate on one XCD (heuristic)
    for (int j = threadIdx.x; j < SLICE_SIZE; j += SCAN_THREADS) acc[j] = 0.0f;
    for (int j = threadIdx.x; j < nparams; j += SCAN_THREADS) pw_lds[j] = PW[j];
    __syncthreads();

    const int4* rp = rows4   + (size_t)c * e4_per_chunk;
    const int4* cp = cols4   + (size_t)c * e4_per_chunk;
    const int4* qp = params4 + (size_t)c * e4_per_chunk;
    const int per_thread = e4_per_chunk / SCAN_THREADS;   // 128

    for (int base = 0; base < per_thread; base += BATCH) {
        int4 r[BATCH], cc[BATCH], pp[BATCH];
#pragma unroll
        for (int b = 0; b < BATCH; ++b) {
            const int g = (base + b) * SCAN_THREADS + threadIdx.x;
            r[b]  = rp[g];
            cc[b] = cp[g];
            pp[b] = qp[g];
        }
#pragma unroll
        for (int b = 0; b < BATCH; ++b) {
            if ((r[b].x >> SLICE_BITS) == s)
                atomicAdd(&acc[r[b].x & (SLICE_SIZE - 1)], pw_lds[pp[b].x] * x[cc[b].x]);
            if ((r[b].y >> SLICE_BITS) == s)
                atomicAdd(&acc[r[b].y & (SLICE_SIZE - 1)], pw_lds[pp[b].y] * x[cc[b].y]);
            if ((r[b].z >> SLICE_BITS) == s)
                atomicAdd(&acc[r[b].z & (SLICE_SIZE - 1)], pw_lds[pp[b].z] * x[cc[b].z]);
            if ((r[b].w >> SLICE_BITS) == s)
                atomicAdd(&acc[r[b].w & (SLICE_SIZE - 1)], pw_lds[pp[b].w] * x[cc[b].w]);
        }
    }
    __syncthreads();

    float* dst = partials + (size_t)bid * SLICE_SIZE;
    for (int j = threadIdx.x; j < SLICE_SIZE; j += SCAN_THREADS) dst[j] = acc[j];
}

__global__ __launch_bounds__(256) void reduce_bias_kernel(
    const float* __restrict__ partials, const float* __restrict__ Pb,
    const int* __restrict__ bp, float* __restrict__ out, int n)
{
    const int i = blockIdx.x * 256 + threadIdx.x;
    if (i >= n) return;
    const int s = i >> SLICE_BITS;
    const int j = i & (SLICE_SIZE - 1);
    const float* p = partials + ((size_t)s * CHUNKS) * SLICE_SIZE + j;
    float sum = 0.0f;
#pragma unroll
    for (int g = 0; g < CHUNKS; ++g) sum += p[(size_t)g * SLICE_SIZE];
    out[i] = sum + Pb[bp[i]];
}

// ---------------- fallback path (round-1 atomic scatter) ----------------

__global__ __launch_bounds__(256) void bias_init_kernel(const float* __restrict__ Pb,
                                                        const int* __restrict__ bp,
                                                        float* __restrict__ out, int n) {
    int i = blockIdx.x * 256 + threadIdx.x;
    if (i < n) out[i] = Pb[bp[i]];
}

__global__ __launch_bounds__(256) void edge_scatter_kernel(const float* __restrict__ x,
                                                           const float* __restrict__ PW,
                                                           const int* __restrict__ rows,
                                                           const int* __restrict__ cols,
                                                           const int* __restrict__ params,
                                                           float* __restrict__ out, int E) {
    int e = blockIdx.x * 256 + threadIdx.x;
    if (e < E) atomicAdd(out + rows[e], PW[params[e]] * x[cols[e]]);
}

extern "C" void kernel_launch(void* const* d_in, const int* in_sizes, int n_in,
                              void* d_out, int out_size, void* d_ws, size_t ws_size,
                              hipStream_t stream) {
    const float* x        = (const float*)d_in[0];
    const float* Param_W  = (const float*)d_in[1];
    const float* Param_b  = (const float*)d_in[2];
    const int*   w_rows   = (const int*)d_in[3];
    const int*   w_cols   = (const int*)d_in[4];
    const int*   w_params = (const int*)d_in[5];
    const int*   b_params = (const int*)d_in[6];
    float* out = (float*)d_out;

    const int N_  = in_sizes[0];   // 262144
    const int NP_ = in_sizes[1];   // 1280
    const int E_  = in_sizes[3];   // 16777216

    const size_t ws_needed = (size_t)SLICES * CHUNKS * SLICE_SIZE * sizeof(float); // 32 MiB
    const bool shape_ok = (N_ == SLICES * SLICE_SIZE) &&
                          (E_ % (4 * CHUNKS * SCAN_THREADS * BATCH) == 0) &&
                          (NP_ <= NPARAMS_MAX);

    if (shape_ok && ws_size >= ws_needed) {
        float* partials = (float*)d_ws;
        const int e4_per_chunk = E_ / 4 / CHUNKS;   // 131072
        slice_scan_kernel<<<SLICES * CHUNKS, SCAN_THREADS, 0, stream>>>(
            x, Param_W, NP_, (const int4*)w_rows, (const int4*)w_cols,
            (const int4*)w_params, partials, e4_per_chunk);
        reduce_bias_kernel<<<(N_ + 255) / 256, 256, 0, stream>>>(
            partials, Param_b, b_params, out, N_);
    } else {
        bias_init_kernel<<<(N_ + 255) / 256, 256, 0, stream>>>(Param_b, b_params, out, N_);
        edge_scatter_kernel<<<(E_ + 255) / 256, 256, 0, stream>>>(
            x, Param_W, w_rows, w_cols, w_params, out, E_);
    }
}